// Round 7
// baseline (454.256 us; speedup 1.0000x reference)
//
#include <hip/hip_runtime.h>
#include <math.h>

// N=50000 nodes, E=800000 edges, F_IN=33, H=128, G=64 graphs.
static constexpr int F_IN = 33;
static constexpr int H    = 128;
static constexpr int GG   = 64;

typedef __attribute__((ext_vector_type(4))) float f32x4;

// fp8 e4m3 (OCP on gfx950) encode/decode via HW cvt.
__device__ __forceinline__ unsigned char f2fp8(float f) {
  int pk = __builtin_amdgcn_cvt_pk_fp8_f32(f, f, 0, false);
  return (unsigned char)(pk & 0xff);
}

// Async global->LDS copy, 16B per lane, wave-uniform LDS base (lane-linear).
using gas_u32 = const __attribute__((address_space(1))) unsigned int*;
using las_u32 = __attribute__((address_space(3))) unsigned int*;
__device__ __forceinline__ void ld_lds16(const unsigned char* g, unsigned char* l) {
  __builtin_amdgcn_global_load_lds((gas_u32)(const void*)g, (las_u32)(void*)l, 16, 0, 0);
}

// ---------------- prep2: deg hist + W conv(fp8) + x conv + red zero ---------
// R6 lesson: keep WIDE grids for this heavy phase (cooperative 256-block cap
// lost 15x parallelism -> 150us). deg[] is pre-zeroed by hipMemsetAsync.

struct PrepArgs {
  const int* dst; int* deg; int E; int NBLK;
  const float* w[6]; unsigned char* o[6]; int K[6]; int Kp[6];
  const float* x; unsigned char* x8; int N; int XB;
  float* red;                               // 3 * GG * H f32, zeroed here
};

__global__ void prep2(PrepArgs a) {
  const int b = blockIdx.x, tx = threadIdx.x;
  if (b < a.NBLK) {
    // per-node degree histogram: global atomics on 200KB L2-resident array
    const int chunk = (a.E + a.NBLK - 1) / a.NBLK;
    const int lo = b * chunk;
    const int hi = min(lo + chunk, a.E);
    for (int i = lo + tx; i < hi; i += 256)
      atomicAdd(&a.deg[a.dst[i]], 1);
  } else if (b < a.NBLK + 384) {
    // W -> fp8, row nn = Kp bytes, 16B chunk c stored at c ^ (nn & (Kp/16-1))
    const int wb = b - a.NBLK;
    const int wi = wb >> 6;
    const int Kp = a.Kp[wi];
    const int i = (wb & 63) * 256 + tx;
    if (i < H * Kp) {
      const int nn = i / Kp, k = i - nn * Kp;
      float v = (k < a.K[wi]) ? a.w[wi][(size_t)k * H + nn] : 0.f;
      a.o[wi][(size_t)nn * Kp + (((k >> 4) ^ (nn & (Kp / 16 - 1))) << 4) + (k & 15)] = f2fp8(v);
    }
  } else if (b < a.NBLK + 384 + a.XB) {
    // x -> fp8, N x 64 rows (64B), 4 chunks of 16B, chunk c at c^(node&3)
    const int xb = b - a.NBLK - 384;
    for (int r = 0; r < 4; ++r) {
      const int idx = xb * 1024 + r * 256 + tx;
      const int node = idx >> 6, f = idx & 63;
      if (node < a.N) {
        float v = (f < F_IN) ? a.x[(size_t)node * F_IN + f] : 0.f;
        a.x8[(size_t)node * 64 + (((f >> 4) ^ (node & 3)) << 4) + (f & 15)] = f2fp8(v);
      }
    }
  } else {
    // zero red: 24 blocks x 256 threads x f32x4 = 3*GG*H floats
    const int zb = b - a.NBLK - 384 - a.XB;
    f32x4* r4 = (f32x4*)a.red;
    r4[zb * 256 + tx] = (f32x4)(0.f);
  }
}

// ---------------- scanN: rowptr + cursor from deg (one block) ---------------

__global__ __launch_bounds__(1024) void scanN(const int* __restrict__ deg,
                                              int* __restrict__ rowptr,
                                              int* __restrict__ cur,
                                              int n, int E) {
  __shared__ int part[1024];
  const int t = threadIdx.x;
  const int chunk = (n + 1023) / 1024;
  const int lo = t * chunk, hi = min(lo + chunk, n);
  int s = 0;
  for (int i = lo; i < hi; ++i) s += deg[i];
  part[t] = s;
  __syncthreads();
  for (int off = 1; off < 1024; off <<= 1) {
    int add = (t >= off) ? part[t - off] : 0;
    __syncthreads();
    part[t] += add;
    __syncthreads();
  }
  int run = part[t] - s;                  // exclusive prefix of this chunk
  for (int i = lo; i < hi; ++i) {
    rowptr[i] = run;
    cur[i] = run;
    run += deg[i];
  }
  if (t == 0) rowptr[n] = E;
}

// ---------------- csr_scatter: direct scatter into srcList ------------------
// Replaces bucket-sort (csr_p2+csr_p3, ~16MB tmp traffic). srcList order
// within a node is arbitrary (atomic) - gather sums are order-invariant.

__global__ void csr_scatter(const int* __restrict__ src, const int* __restrict__ dst,
                            int* __restrict__ cur, int* __restrict__ srcList, int E) {
  int i = blockIdx.x * blockDim.x + threadIdx.x;
  const int stride = gridDim.x * blockDim.x;
  for (; i < E; i += stride) {
    int pos = atomicAdd(&cur[dst[i]], 1);
    srcList[pos] = src[i];
  }
}

// ---------------- Aggregation (gather), fp8 rows -> fp8 out -----------------
// Line-throughput bound (R2/R3/R5 evidence). R4 known-good form.

__global__ void gather_h(const unsigned char* __restrict__ h8, const int* __restrict__ rowptr,
                         const int* __restrict__ srcList, unsigned char* __restrict__ out, int n) {
  const int tx = threadIdx.x;
  const int node = blockIdx.x * 32 + (tx >> 3);   // 8-lane group per node
  if (node >= n) return;
  const int lane = tx & 63;
  const int l8 = lane & 7;                // 16B chunk within fp8 row
  const int gbase = lane & 56;
  const uint4* h16 = (const uint4*)h8;    // fp8 row = 8 uint4 (128B)
  auto roff = [&](int r) { return (size_t)r * 8 + (l8 ^ (r & 7)); };

  const int beg = rowptr[node], end = rowptr[node + 1];
  float a[16];
#pragma unroll
  for (int i = 0; i < 16; ++i) a[i] = 0.f;
  auto addv = [&](uint4 vv) {
    const unsigned* w = (const unsigned*)&vv;
#pragma unroll
    for (int c = 0; c < 4; ++c) {
      a[c * 4 + 0] += __builtin_amdgcn_cvt_f32_fp8(w[c], 0);
      a[c * 4 + 1] += __builtin_amdgcn_cvt_f32_fp8(w[c], 1);
      a[c * 4 + 2] += __builtin_amdgcn_cvt_f32_fp8(w[c], 2);
      a[c * 4 + 3] += __builtin_amdgcn_cvt_f32_fp8(w[c], 3);
    }
  };

  for (int base = beg; base < end; base += 8) {
    const int cnt = min(8, end - base);
    int myidx = (l8 < cnt) ? srcList[base + l8] : 0;
#pragma unroll
    for (int j = 0; j < 8; j += 4) {
      if (j >= cnt) break;
      int s[4]; uint4 v[4];
#pragma unroll
      for (int k = 0; k < 4; ++k) s[k] = __shfl(myidx, gbase + min(j + k, cnt - 1));
#pragma unroll
      for (int k = 0; k < 4; ++k) v[k] = h16[roff(s[k])];
#pragma unroll
      for (int k = 0; k < 4; ++k) if (j + k < cnt) addv(v[k]);
    }
  }
  addv(h16[roff(node)]);                  // self term
  // 16 f32 -> 16 fp8 bytes = this lane's 16B chunk l8 of the A row
  unsigned w0 = __builtin_amdgcn_cvt_pk_fp8_f32(a[0], a[1], 0, false);
  w0 = __builtin_amdgcn_cvt_pk_fp8_f32(a[2], a[3], w0, true);
  unsigned w1 = __builtin_amdgcn_cvt_pk_fp8_f32(a[4], a[5], 0, false);
  w1 = __builtin_amdgcn_cvt_pk_fp8_f32(a[6], a[7], w1, true);
  unsigned w2 = __builtin_amdgcn_cvt_pk_fp8_f32(a[8], a[9], 0, false);
  w2 = __builtin_amdgcn_cvt_pk_fp8_f32(a[10], a[11], w2, true);
  unsigned w3 = __builtin_amdgcn_cvt_pk_fp8_f32(a[12], a[13], 0, false);
  w3 = __builtin_amdgcn_cvt_pk_fp8_f32(a[14], a[15], w3, true);
  uint4 o; o.x = w0; o.y = w1; o.z = w2; o.w = w3;
  ((uint4*)out)[(size_t)node * 8 + (l8 ^ (node & 7))] = o;
}

// Layer-1 gather on x8 (fp8 Nx64 swizzled, 64B rows = 4 uint4) -> A fp8 64B.

__global__ void gather_x4(const unsigned char* __restrict__ x8, const int* __restrict__ rowptr,
                          const int* __restrict__ srcList, unsigned char* __restrict__ out, int n) {
  const int tx = threadIdx.x;
  const int node = blockIdx.x * 64 + (tx >> 2);   // 4-lane group per node
  if (node >= n) return;
  const int lane = tx & 63;
  const int l4 = lane & 3;                // 16B chunk within fp8 row
  const int gbase = lane & 60;
  const uint4* h16 = (const uint4*)x8;    // fp8 row = 4 uint4 (64B)
  auto roff = [&](int r) { return (size_t)r * 4 + (l4 ^ (r & 3)); };

  const int beg = rowptr[node], end = rowptr[node + 1];
  float a[16];
#pragma unroll
  for (int i = 0; i < 16; ++i) a[i] = 0.f;
  auto addv = [&](uint4 vv) {
    const unsigned* w = (const unsigned*)&vv;
#pragma unroll
    for (int c = 0; c < 4; ++c) {
      a[c * 4 + 0] += __builtin_amdgcn_cvt_f32_fp8(w[c], 0);
      a[c * 4 + 1] += __builtin_amdgcn_cvt_f32_fp8(w[c], 1);
      a[c * 4 + 2] += __builtin_amdgcn_cvt_f32_fp8(w[c], 2);
      a[c * 4 + 3] += __builtin_amdgcn_cvt_f32_fp8(w[c], 3);
    }
  };

  for (int base = beg; base < end; base += 4) {
    const int cnt = min(4, end - base);
    int myidx = (l4 < cnt) ? srcList[base + l4] : 0;
    int s[4]; uint4 v[4];
#pragma unroll
    for (int k = 0; k < 4; ++k) s[k] = __shfl(myidx, gbase + min(k, cnt - 1));
#pragma unroll
    for (int k = 0; k < 4; ++k) v[k] = h16[roff(s[k])];
#pragma unroll
    for (int k = 0; k < 4; ++k) if (k < cnt) addv(v[k]);
  }
  addv(h16[roff(node)]);                  // self term
  unsigned w0 = __builtin_amdgcn_cvt_pk_fp8_f32(a[0], a[1], 0, false);
  w0 = __builtin_amdgcn_cvt_pk_fp8_f32(a[2], a[3], w0, true);
  unsigned w1 = __builtin_amdgcn_cvt_pk_fp8_f32(a[4], a[5], 0, false);
  w1 = __builtin_amdgcn_cvt_pk_fp8_f32(a[6], a[7], w1, true);
  unsigned w2 = __builtin_amdgcn_cvt_pk_fp8_f32(a[8], a[9], 0, false);
  w2 = __builtin_amdgcn_cvt_pk_fp8_f32(a[10], a[11], w2, true);
  unsigned w3 = __builtin_amdgcn_cvt_pk_fp8_f32(a[12], a[13], 0, false);
  w3 = __builtin_amdgcn_cvt_pk_fp8_f32(a[14], a[15], w3, true);
  uint4 o; o.x = w0; o.y = w1; o.z = w2; o.w = w3;
  ((uint4*)out)[(size_t)node * 4 + (l4 ^ (node & 3))] = o;
}

// -------- Fused GIN MLP (all-fp8): C = relu(relu(BN(A@W1)) @ W2 + b2) -------
// fp8 MFMA + fp8 LDS tiles + 4-graph local pool (R4 known-good).

template <int K1, bool STORE>
__global__ __launch_bounds__(512, 4) void gin_mlp(
    const unsigned char* __restrict__ Ag,    // n x K1 fp8 (swizzled rows)
    const unsigned char* __restrict__ W1t,   // 128 x K1 fp8 (swizzled)
    const unsigned char* __restrict__ W2t,   // 128 x 128 fp8 (swizzled)
    const float* __restrict__ b1, const float* __restrict__ gam,
    const float* __restrict__ bet, const float* __restrict__ mu,
    const float* __restrict__ var, const float* __restrict__ b2,
    unsigned char* __restrict__ Pout,        // n x 128 fp8 (swizzled) or null
    const int* __restrict__ batch,
    float* __restrict__ red,                 // GG*H f32, pre-zeroed; atomic dst
    int n) {
  constexpr int CM1 = K1 / 16 - 1;           // A/W1 chunk-swizzle mask
  __shared__ __align__(16) unsigned char W1ls[128 * K1];
  __shared__ __align__(16) unsigned char W2ls[128 * 128];
  __shared__ __align__(16) unsigned char Als[64 * K1];
  __shared__ __align__(16) unsigned char Zls[64 * 128];
  __shared__ float poolLs[4 * H];            // 2 KB local-graph pool window
  __shared__ float sc1[128], sh1[128], b2l[128];

  const int tx = threadIdx.x;
  const int wv = tx >> 6;                 // wave 0..7
  const int lane = tx & 63;
  const int q = lane >> 4, m = lane & 15;
  const int rowGroup = (wv >> 1) * 16;    // 0,16,32,48
  const int colHalf = (wv & 1) * 64;
  const int ntiles = (n + 63) >> 6;
  // contiguous tile range for this block
  const int t0 = (int)(((long long)ntiles * blockIdx.x) / gridDim.x);
  const int t1 = (int)(((long long)ntiles * (blockIdx.x + 1)) / gridDim.x);
  const int glo = (t0 < t1) ? batch[t0 * 64] : 0;   // local pool base graph

  // Stage W once (async; each wave copies distinct 1024B segments).
  constexpr int W1SEG = 128 * K1 / 1024;
  for (int s = wv; s < W1SEG; s += 8)
    ld_lds16(W1t + s * 1024 + lane * 16, &W1ls[s * 1024]);
  for (int s = wv; s < 16; s += 8)
    ld_lds16(W2t + s * 1024 + lane * 16, &W2ls[s * 1024]);

  // Zero local pool (512 floats, one per thread).
  poolLs[tx] = 0.f;
  if (tx < 128) {                          // fold bias1 into BN affine
    float s = gam[tx] * rsqrtf(var[tx] + 1e-5f);
    sc1[tx] = s;
    sh1[tx] = bet[tx] + (b1[tx] - mu[tx]) * s;
  } else if (tx < 256) {
    b2l[tx - 128] = b2[tx - 128];
  }

  int tile = t0;
  constexpr int ASEG = 64 * K1 / 1024;
  if (tile < t1) {
    const unsigned char* srcp = Ag + (size_t)tile * 64 * K1;
    for (int s = wv; s < ASEG; s += 8)
      ld_lds16(srcp + s * 1024 + lane * 16, &Als[s * 1024]);
  }
  __syncthreads();                         // drains W + A(tile)

  while (tile < t1) {
    // ---- GEMM1: Z = relu(BN(A @ W1 + b1)) ----
    f32x4 acc[4];
#pragma unroll
    for (int t4 = 0; t4 < 4; ++t4) acc[t4] = (f32x4)(0.f);
    const int am = rowGroup + m;
#pragma unroll
    for (int kc = 0; kc < K1 / 32; ++kc) {
      const int c16 = kc * 2 + (q >> 1);
      const int hb = (q & 1) << 3;
      long af = *(const long*)&Als[am * K1 + ((c16 ^ (am & CM1)) << 4) + hb];
#pragma unroll
      for (int t4 = 0; t4 < 4; ++t4) {
        const int bn = colHalf + t4 * 16 + m;
        long bf = *(const long*)&W1ls[bn * K1 + ((c16 ^ (bn & CM1)) << 4) + hb];
        acc[t4] = __builtin_amdgcn_mfma_f32_16x16x32_fp8_fp8(af, bf, acc[t4], 0, 0, 0);
      }
    }
#pragma unroll
    for (int t4 = 0; t4 < 4; ++t4) {       // epilogue -> Zls (fp8, swizzled)
      const int col = colHalf + t4 * 16 + m;
      const float s = sc1[col], hh = sh1[col];
#pragma unroll
      for (int reg = 0; reg < 4; ++reg) {
        const int r = rowGroup + q * 4 + reg;
        float z = fmaf(acc[t4][reg], s, hh);
        z = z > 0.f ? z : 0.f;
        Zls[r * 128 + (((col >> 4) ^ (r & 7)) << 4) + (col & 15)] = f2fp8(z);
      }
    }
    __syncthreads();                       // Zls ready; Als free
    const int nt = tile + 1;
    if (nt < t1) {                         // prefetch next A, overlaps GEMM2
      const unsigned char* srcp = Ag + (size_t)nt * 64 * K1;
      for (int s = wv; s < ASEG; s += 8)
        ld_lds16(srcp + s * 1024 + lane * 16, &Als[s * 1024]);
    }
    // ---- GEMM2: C = relu(Z @ W2 + b2) ----
#pragma unroll
    for (int t4 = 0; t4 < 4; ++t4) acc[t4] = (f32x4)(0.f);
#pragma unroll
    for (int kc = 0; kc < 4; ++kc) {
      const int c16 = kc * 2 + (q >> 1);
      const int hb = (q & 1) << 3;
      long af = *(const long*)&Zls[am * 128 + ((c16 ^ (am & 7)) << 4) + hb];
#pragma unroll
      for (int t4 = 0; t4 < 4; ++t4) {
        const int bn = colHalf + t4 * 16 + m;
        long bf = *(const long*)&W2ls[bn * 128 + ((c16 ^ (bn & 7)) << 4) + hb];
        acc[t4] = __builtin_amdgcn_mfma_f32_16x16x32_fp8_fp8(af, bf, acc[t4], 0, 0, 0);
      }
    }
    const int r0 = tile * 64 + rowGroup + q * 4;
    int gb4[4];
#pragma unroll
    for (int reg = 0; reg < 4; ++reg) gb4[reg] = (r0 + reg < n) ? batch[r0 + reg] : -1;
#pragma unroll
    for (int t4 = 0; t4 < 4; ++t4) {
      const int col = colHalf + t4 * 16 + m;
      float v[4];
#pragma unroll
      for (int reg = 0; reg < 4; ++reg) {
        float z = acc[t4][reg] + b2l[col];
        v[reg] = z > 0.f ? z : 0.f;
      }
      if constexpr (STORE) {
        // fp8 row: chunk (col>>4)^(row&7), byte col&15 (matches gather_h)
#pragma unroll
        for (int reg = 0; reg < 4; ++reg) {
          const int row = r0 + reg;
          if (row < n)
            Pout[(size_t)row * 128 + (((col >> 4) ^ (row & 7)) << 4) + (col & 15)] = f2fp8(v[reg]);
        }
      }
      int gcur = -1; float ps = 0.f;       // batch sorted -> run-length flush
#pragma unroll
      for (int reg = 0; reg < 4; ++reg) {
        if (gb4[reg] < 0) break;
        if (gb4[reg] != gcur) {
          if (gcur >= 0) {
            const int li = gcur - glo;
            if (li < 4) atomicAdd(&poolLs[li * H + col], ps);
            else        atomicAdd(&red[gcur * H + col], ps);
          }
          gcur = gb4[reg]; ps = v[reg];
        } else {
          ps += v[reg];
        }
      }
      if (gcur >= 0) {
        const int li = gcur - glo;
        if (li < 4) atomicAdd(&poolLs[li * H + col], ps);
        else        atomicAdd(&red[gcur * H + col], ps);
      }
    }
    __syncthreads();                       // drains prefetch; Zls free
    tile = nt;
  }

  // Flush local pool window (<=4 graphs) to global red.
  if (t0 < t1) {
    const int rhi = min(t1 * 64, n) - 1;
    const int ng = min(batch[rhi] - glo + 1, 4);
    for (int i = tx; i < ng * H; i += 512)
      atomicAdd(&red[glo * H + i], poolLs[i]);
  }
}

// ------- Head: read reduced pools + MLP + sigmoid ---------------------------

__global__ void head2(const float* __restrict__ red,
                      const float* __restrict__ l1w, const float* __restrict__ l1b,
                      const float* __restrict__ l2w, const float* __restrict__ l2b,
                      const float* __restrict__ l3w, const float* __restrict__ l3b,
                      float* __restrict__ out) {
  const int g = blockIdx.x;
  const int t = threadIdx.x;  // 256 threads
  __shared__ float hin[3 * H];
  __shared__ float t1[50];
  __shared__ float t2[20];
  for (int idx = t; idx < 3 * H; idx += 256) {
    const int l = idx >> 7, f = idx & 127;
    hin[idx] = red[(size_t)l * (GG * H) + (size_t)g * H + f];
  }
  __syncthreads();
  if (t < 50) {
    float s = l1b[t];
    for (int k = 0; k < 3 * H; ++k) s = fmaf(hin[k], l1w[k * 50 + t], s);
    t1[t] = s > 0.f ? s : 0.f;
  }
  __syncthreads();
  if (t < 20) {
    float s = l2b[t];
    for (int k = 0; k < 50; ++k) s = fmaf(t1[k], l2w[k * 20 + t], s);
    t2[t] = s > 0.f ? s : 0.f;
  }
  __syncthreads();
  if (t == 0) {
    float s = l3b[0];
    for (int k = 0; k < 20; ++k) s = fmaf(t2[k], l3w[k], s);
    out[g] = 1.f / (1.f + expf(-s));
  }
}

// ---------------- launch ----------------------------------------------------

extern "C" void kernel_launch(void* const* d_in, const int* in_sizes, int n_in,
                              void* d_out, int out_size, void* d_ws, size_t ws_size,
                              hipStream_t stream) {
  const float* x    = (const float*)d_in[0];
  const int* ei     = (const int*)d_in[1];
  const int* batch  = (const int*)d_in[2];
  const int N = in_sizes[2];
  const int E = in_sizes[1] / 2;
  const int* src = ei;
  const int* dst = ei + E;

  const float* w1[3]; const float* b1[3]; const float* gm[3]; const float* be[3];
  const float* mu[3]; const float* vr[3]; const float* w2[3]; const float* b2[3];
  for (int l = 0; l < 3; ++l) {
    int b = 3 + 8 * l;
    w1[l] = (const float*)d_in[b + 0];
    b1[l] = (const float*)d_in[b + 1];
    gm[l] = (const float*)d_in[b + 2];
    be[l] = (const float*)d_in[b + 3];
    mu[l] = (const float*)d_in[b + 4];
    vr[l] = (const float*)d_in[b + 5];
    w2[l] = (const float*)d_in[b + 6];
    b2[l] = (const float*)d_in[b + 7];
  }
  const float* l1w = (const float*)d_in[27];
  const float* l1b = (const float*)d_in[28];
  const float* l2w = (const float*)d_in[29];
  const float* l2b = (const float*)d_in[30];
  const float* l3w = (const float*)d_in[31];
  const float* l3b = (const float*)d_in[32];

  // workspace carve-up
  char* ws = (char*)d_ws;
  size_t off = 0;
  auto take = [&](size_t bytes) {
    size_t p = off;
    off += (bytes + 255) & ~(size_t)255;
    return p;
  };
  unsigned char* A   = (unsigned char*)(ws + take((size_t)N * H));        // agg (fp8, swizzled)
  unsigned char* P   = (unsigned char*)(ws + take((size_t)N * H));        // layer out (fp8, swizzled)
  unsigned char* x8  = (unsigned char*)(ws + take((size_t)N * 64));       // x as fp8 Nx64 swizzled
  float* red    = (float*)(ws + take((size_t)3 * GG * H * 4));            // 96 KB pooled sums
  int* rowptr   = (int*)(ws + take((size_t)(N + 1) * 4));
  int* deg      = (int*)(ws + take((size_t)N * 4));                       // node degrees
  int* cur      = (int*)(ws + take((size_t)N * 4));                       // scatter cursors
  int* srcList  = (int*)(ws + take((size_t)E * 4));
  unsigned char* Wt[6];
  for (int i = 0; i < 6; ++i) Wt[i] = (unsigned char*)(ws + take((size_t)H * H));
  (void)ws_size; (void)n_in; (void)out_size;

  const int NBLK = 256;
  const int XB = ((size_t)N * 64 + 1023) / 1024;
  const int GBH = (N + 31) / 32;          // gather_h blocks (32 nodes each)
  const int GBX = (N + 63) / 64;          // gather_x4 blocks (64 nodes each)

  // zero degree array (capture-legal async fill)
  hipMemsetAsync(deg, 0, (size_t)N * 4, stream);

  // prep2: deg hist + wconv + xconv + red zero, one wide launch
  PrepArgs pa;
  pa.dst = dst; pa.deg = deg; pa.E = E; pa.NBLK = NBLK;
  pa.w[0] = w1[0]; pa.K[0] = F_IN; pa.Kp[0] = 64;
  pa.w[1] = w2[0]; pa.K[1] = H;    pa.Kp[1] = H;
  pa.w[2] = w1[1]; pa.K[2] = H;    pa.Kp[2] = H;
  pa.w[3] = w2[1]; pa.K[3] = H;    pa.Kp[3] = H;
  pa.w[4] = w1[2]; pa.K[4] = H;    pa.Kp[4] = H;
  pa.w[5] = w2[2]; pa.K[5] = H;    pa.Kp[5] = H;
  for (int i = 0; i < 6; ++i) pa.o[i] = Wt[i];
  pa.x = x; pa.x8 = x8; pa.N = N; pa.XB = XB;
  pa.red = red;
  prep2<<<NBLK + 384 + XB + 24, 256, 0, stream>>>(pa);

  // CSR: rowptr/cursors from deg (1 block), then direct scatter
  scanN<<<1, 1024, 0, stream>>>(deg, rowptr, cur, N, E);
  csr_scatter<<<1024, 256, 0, stream>>>(src, dst, cur, srcList, E);

  // ---- layer 1 (K padded 33 -> 64) ----
  gather_x4<<<GBX, 256, 0, stream>>>(x8, rowptr, srcList, A, N);
  gin_mlp<64, true><<<512, 512, 0, stream>>>(
      A, Wt[0], Wt[1], b1[0], gm[0], be[0], mu[0], vr[0], b2[0],
      P, batch, red, N);

  // ---- layer 2 ----
  gather_h<<<GBH, 256, 0, stream>>>(P, rowptr, srcList, A, N);
  gin_mlp<128, true><<<512, 512, 0, stream>>>(
      A, Wt[2], Wt[3], b1[1], gm[1], be[1], mu[1], vr[1], b2[1],
      P, batch, red + (size_t)GG * H, N);

  // ---- layer 3 (h3 pooled only) ----
  gather_h<<<GBH, 256, 0, stream>>>(P, rowptr, srcList, A, N);
  gin_mlp<128, false><<<512, 512, 0, stream>>>(
      A, Wt[4], Wt[5], b1[2], gm[2], be[2], mu[2], vr[2], b2[2],
      nullptr, batch, red + (size_t)2 * GG * H, N);

  // ---- head (read reduced pools + MLP + sigmoid) ----
  head2<<<GG, 256, 0, stream>>>(red, l1w, l1b, l2w, l2b, l3w, l3b, (float*)d_out);
}

// Round 8
// 340.885 us; speedup vs baseline: 1.3326x; 1.3326x over previous
//
#include <hip/hip_runtime.h>
#include <math.h>

// N=50000 nodes, E=800000 edges, F_IN=33, H=128, G=64 graphs.
static constexpr int F_IN = 33;
static constexpr int H    = 128;
static constexpr int GG   = 64;

typedef __attribute__((ext_vector_type(4))) float f32x4;

// fp8 e4m3 (OCP on gfx950) encode/decode via HW cvt.
__device__ __forceinline__ unsigned char f2fp8(float f) {
  int pk = __builtin_amdgcn_cvt_pk_fp8_f32(f, f, 0, false);
  return (unsigned char)(pk & 0xff);
}

// Async global->LDS copy, 16B per lane, wave-uniform LDS base (lane-linear).
using gas_u32 = const __attribute__((address_space(1))) unsigned int*;
using las_u32 = __attribute__((address_space(3))) unsigned int*;
__device__ __forceinline__ void ld_lds16(const unsigned char* g, unsigned char* l) {
  __builtin_amdgcn_global_load_lds((gas_u32)(const void*)g, (las_u32)(void*)l, 16, 0, 0);
}

// ---------------- prep2: deg hist + W conv(fp8) + x conv + red zero ---------
// R6 lesson: keep WIDE grids. deg[] pre-zeroed by hipMemsetAsync.

struct PrepArgs {
  const int* dst; int* deg; int E; int NBLK;
  const float* w[6]; unsigned char* o[6]; int K[6]; int Kp[6];
  const float* x; unsigned char* x8; int N; int XB;
  float* red;                               // 3 * GG * H f32, zeroed here
};

__global__ void prep2(PrepArgs a) {
  const int b = blockIdx.x, tx = threadIdx.x;
  if (b < a.NBLK) {
    // per-node degree histogram: global atomics on 200KB L2-resident array
    const int chunk = (a.E + a.NBLK - 1) / a.NBLK;
    const int lo = b * chunk;
    const int hi = min(lo + chunk, a.E);
    for (int i = lo + tx; i < hi; i += 256)
      atomicAdd(&a.deg[a.dst[i]], 1);
  } else if (b < a.NBLK + 384) {
    // W -> fp8, row nn = Kp bytes, 16B chunk c stored at c ^ (nn & (Kp/16-1))
    const int wb = b - a.NBLK;
    const int wi = wb >> 6;
    const int Kp = a.Kp[wi];
    const int i = (wb & 63) * 256 + tx;
    if (i < H * Kp) {
      const int nn = i / Kp, k = i - nn * Kp;
      float v = (k < a.K[wi]) ? a.w[wi][(size_t)k * H + nn] : 0.f;
      a.o[wi][(size_t)nn * Kp + (((k >> 4) ^ (nn & (Kp / 16 - 1))) << 4) + (k & 15)] = f2fp8(v);
    }
  } else if (b < a.NBLK + 384 + a.XB) {
    // x -> fp8, N x 64 rows (64B), 4 chunks of 16B, chunk c at c^(node&3)
    const int xb = b - a.NBLK - 384;
    for (int r = 0; r < 4; ++r) {
      const int idx = xb * 1024 + r * 256 + tx;
      const int node = idx >> 6, f = idx & 63;
      if (node < a.N) {
        float v = (f < F_IN) ? a.x[(size_t)node * F_IN + f] : 0.f;
        a.x8[(size_t)node * 64 + (((f >> 4) ^ (node & 3)) << 4) + (f & 15)] = f2fp8(v);
      }
    }
  } else {
    // zero red: 24 blocks x 256 threads x f32x4 = 3*GG*H floats
    const int zb = b - a.NBLK - 384 - a.XB;
    f32x4* r4 = (f32x4*)a.red;
    r4[zb * 256 + tx] = (f32x4)(0.f);
  }
}

// ---------------- hierarchical scan: deg -> rowptr + cur --------------------
// R7 lesson: a single-block serial scan = 111us latency trap. Use the proven
// scanA idiom: wide 256-thread LDS scans, block totals, redundant totals-scan
// per block in pass 2 (no grid sync needed; 196 values is trivial).

__global__ void scanB(const int* __restrict__ deg, int* __restrict__ blockTotal, int n) {
  __shared__ int scn[256];
  const int b = blockIdx.x, t = threadIdx.x;
  const int i = b * 256 + t;
  int v = (i < n) ? deg[i] : 0;
  scn[t] = v;
  __syncthreads();
  for (int off = 1; off < 256; off <<= 1) {
    int add = (t >= off) ? scn[t - off] : 0;
    __syncthreads();
    scn[t] += add;
    __syncthreads();
  }
  if (t == 255) blockTotal[b] = scn[255];
}

__global__ void scanC(const int* __restrict__ deg, const int* __restrict__ blockTotal,
                      int* __restrict__ rowptr, int* __restrict__ cur, int n, int E, int SB) {
  __shared__ int tot[256];
  __shared__ int scn[256];
  const int b = blockIdx.x, t = threadIdx.x;
  // redundant exclusive scan of block totals -> this block's base offset
  int tv = (t < SB) ? blockTotal[t] : 0;
  tot[t] = tv;
  __syncthreads();
  for (int off = 1; off < 256; off <<= 1) {
    int add = (t >= off) ? tot[t - off] : 0;
    __syncthreads();
    tot[t] += add;
    __syncthreads();
  }
  const int base = tot[b] - ((b < SB) ? blockTotal[b] : 0);  // exclusive prefix
  // within-block scan of deg
  const int i = b * 256 + t;
  int v = (i < n) ? deg[i] : 0;
  scn[t] = v;
  __syncthreads();
  for (int off = 1; off < 256; off <<= 1) {
    int add = (t >= off) ? scn[t - off] : 0;
    __syncthreads();
    scn[t] += add;
    __syncthreads();
  }
  if (i < n) {
    const int r = base + scn[t] - v;      // exclusive
    rowptr[i] = r;
    cur[i] = r;
  }
  if (b == 0 && t == 0) rowptr[n] = E;
}

// ---------------- csr_scatter: direct scatter into srcList ------------------

__global__ void csr_scatter(const int* __restrict__ src, const int* __restrict__ dst,
                            int* __restrict__ cur, int* __restrict__ srcList, int E) {
  int i = blockIdx.x * blockDim.x + threadIdx.x;
  const int stride = gridDim.x * blockDim.x;
  for (; i < E; i += stride) {
    int pos = atomicAdd(&cur[dst[i]], 1);
    srcList[pos] = src[i];
  }
}

// ---------------- Aggregation (gather), fp8 rows -> fp8 out -----------------
// Line-throughput bound (R2/R3/R5 evidence). R4 known-good form.

__global__ void gather_h(const unsigned char* __restrict__ h8, const int* __restrict__ rowptr,
                         const int* __restrict__ srcList, unsigned char* __restrict__ out, int n) {
  const int tx = threadIdx.x;
  const int node = blockIdx.x * 32 + (tx >> 3);   // 8-lane group per node
  if (node >= n) return;
  const int lane = tx & 63;
  const int l8 = lane & 7;                // 16B chunk within fp8 row
  const int gbase = lane & 56;
  const uint4* h16 = (const uint4*)h8;    // fp8 row = 8 uint4 (128B)
  auto roff = [&](int r) { return (size_t)r * 8 + (l8 ^ (r & 7)); };

  const int beg = rowptr[node], end = rowptr[node + 1];
  float a[16];
#pragma unroll
  for (int i = 0; i < 16; ++i) a[i] = 0.f;
  auto addv = [&](uint4 vv) {
    const unsigned* w = (const unsigned*)&vv;
#pragma unroll
    for (int c = 0; c < 4; ++c) {
      a[c * 4 + 0] += __builtin_amdgcn_cvt_f32_fp8(w[c], 0);
      a[c * 4 + 1] += __builtin_amdgcn_cvt_f32_fp8(w[c], 1);
      a[c * 4 + 2] += __builtin_amdgcn_cvt_f32_fp8(w[c], 2);
      a[c * 4 + 3] += __builtin_amdgcn_cvt_f32_fp8(w[c], 3);
    }
  };

  for (int base = beg; base < end; base += 8) {
    const int cnt = min(8, end - base);
    int myidx = (l8 < cnt) ? srcList[base + l8] : 0;
#pragma unroll
    for (int j = 0; j < 8; j += 4) {
      if (j >= cnt) break;
      int s[4]; uint4 v[4];
#pragma unroll
      for (int k = 0; k < 4; ++k) s[k] = __shfl(myidx, gbase + min(j + k, cnt - 1));
#pragma unroll
      for (int k = 0; k < 4; ++k) v[k] = h16[roff(s[k])];
#pragma unroll
      for (int k = 0; k < 4; ++k) if (j + k < cnt) addv(v[k]);
    }
  }
  addv(h16[roff(node)]);                  // self term
  // 16 f32 -> 16 fp8 bytes = this lane's 16B chunk l8 of the A row
  unsigned w0 = __builtin_amdgcn_cvt_pk_fp8_f32(a[0], a[1], 0, false);
  w0 = __builtin_amdgcn_cvt_pk_fp8_f32(a[2], a[3], w0, true);
  unsigned w1 = __builtin_amdgcn_cvt_pk_fp8_f32(a[4], a[5], 0, false);
  w1 = __builtin_amdgcn_cvt_pk_fp8_f32(a[6], a[7], w1, true);
  unsigned w2 = __builtin_amdgcn_cvt_pk_fp8_f32(a[8], a[9], 0, false);
  w2 = __builtin_amdgcn_cvt_pk_fp8_f32(a[10], a[11], w2, true);
  unsigned w3 = __builtin_amdgcn_cvt_pk_fp8_f32(a[12], a[13], 0, false);
  w3 = __builtin_amdgcn_cvt_pk_fp8_f32(a[14], a[15], w3, true);
  uint4 o; o.x = w0; o.y = w1; o.z = w2; o.w = w3;
  ((uint4*)out)[(size_t)node * 8 + (l8 ^ (node & 7))] = o;
}

// Layer-1 gather on x8 (fp8 Nx64 swizzled, 64B rows = 4 uint4) -> A fp8 64B.

__global__ void gather_x4(const unsigned char* __restrict__ x8, const int* __restrict__ rowptr,
                          const int* __restrict__ srcList, unsigned char* __restrict__ out, int n) {
  const int tx = threadIdx.x;
  const int node = blockIdx.x * 64 + (tx >> 2);   // 4-lane group per node
  if (node >= n) return;
  const int lane = tx & 63;
  const int l4 = lane & 3;                // 16B chunk within fp8 row
  const int gbase = lane & 60;
  const uint4* h16 = (const uint4*)x8;    // fp8 row = 4 uint4 (64B)
  auto roff = [&](int r) { return (size_t)r * 4 + (l4 ^ (r & 3)); };

  const int beg = rowptr[node], end = rowptr[node + 1];
  float a[16];
#pragma unroll
  for (int i = 0; i < 16; ++i) a[i] = 0.f;
  auto addv = [&](uint4 vv) {
    const unsigned* w = (const unsigned*)&vv;
#pragma unroll
    for (int c = 0; c < 4; ++c) {
      a[c * 4 + 0] += __builtin_amdgcn_cvt_f32_fp8(w[c], 0);
      a[c * 4 + 1] += __builtin_amdgcn_cvt_f32_fp8(w[c], 1);
      a[c * 4 + 2] += __builtin_amdgcn_cvt_f32_fp8(w[c], 2);
      a[c * 4 + 3] += __builtin_amdgcn_cvt_f32_fp8(w[c], 3);
    }
  };

  for (int base = beg; base < end; base += 4) {
    const int cnt = min(4, end - base);
    int myidx = (l4 < cnt) ? srcList[base + l4] : 0;
    int s[4]; uint4 v[4];
#pragma unroll
    for (int k = 0; k < 4; ++k) s[k] = __shfl(myidx, gbase + min(k, cnt - 1));
#pragma unroll
    for (int k = 0; k < 4; ++k) v[k] = h16[roff(s[k])];
#pragma unroll
    for (int k = 0; k < 4; ++k) if (k < cnt) addv(v[k]);
  }
  addv(h16[roff(node)]);                  // self term
  unsigned w0 = __builtin_amdgcn_cvt_pk_fp8_f32(a[0], a[1], 0, false);
  w0 = __builtin_amdgcn_cvt_pk_fp8_f32(a[2], a[3], w0, true);
  unsigned w1 = __builtin_amdgcn_cvt_pk_fp8_f32(a[4], a[5], 0, false);
  w1 = __builtin_amdgcn_cvt_pk_fp8_f32(a[6], a[7], w1, true);
  unsigned w2 = __builtin_amdgcn_cvt_pk_fp8_f32(a[8], a[9], 0, false);
  w2 = __builtin_amdgcn_cvt_pk_fp8_f32(a[10], a[11], w2, true);
  unsigned w3 = __builtin_amdgcn_cvt_pk_fp8_f32(a[12], a[13], 0, false);
  w3 = __builtin_amdgcn_cvt_pk_fp8_f32(a[14], a[15], w3, true);
  uint4 o; o.x = w0; o.y = w1; o.z = w2; o.w = w3;
  ((uint4*)out)[(size_t)node * 4 + (l4 ^ (node & 3))] = o;
}

// -------- Fused GIN MLP (all-fp8): C = relu(relu(BN(A@W1)) @ W2 + b2) -------
// fp8 MFMA + fp8 LDS tiles + 4-graph local pool (R4 known-good).

template <int K1, bool STORE>
__global__ __launch_bounds__(512, 4) void gin_mlp(
    const unsigned char* __restrict__ Ag,    // n x K1 fp8 (swizzled rows)
    const unsigned char* __restrict__ W1t,   // 128 x K1 fp8 (swizzled)
    const unsigned char* __restrict__ W2t,   // 128 x 128 fp8 (swizzled)
    const float* __restrict__ b1, const float* __restrict__ gam,
    const float* __restrict__ bet, const float* __restrict__ mu,
    const float* __restrict__ var, const float* __restrict__ b2,
    unsigned char* __restrict__ Pout,        // n x 128 fp8 (swizzled) or null
    const int* __restrict__ batch,
    float* __restrict__ red,                 // GG*H f32, pre-zeroed; atomic dst
    int n) {
  constexpr int CM1 = K1 / 16 - 1;           // A/W1 chunk-swizzle mask
  __shared__ __align__(16) unsigned char W1ls[128 * K1];
  __shared__ __align__(16) unsigned char W2ls[128 * 128];
  __shared__ __align__(16) unsigned char Als[64 * K1];
  __shared__ __align__(16) unsigned char Zls[64 * 128];
  __shared__ float poolLs[4 * H];            // 2 KB local-graph pool window
  __shared__ float sc1[128], sh1[128], b2l[128];

  const int tx = threadIdx.x;
  const int wv = tx >> 6;                 // wave 0..7
  const int lane = tx & 63;
  const int q = lane >> 4, m = lane & 15;
  const int rowGroup = (wv >> 1) * 16;    // 0,16,32,48
  const int colHalf = (wv & 1) * 64;
  const int ntiles = (n + 63) >> 6;
  // contiguous tile range for this block
  const int t0 = (int)(((long long)ntiles * blockIdx.x) / gridDim.x);
  const int t1 = (int)(((long long)ntiles * (blockIdx.x + 1)) / gridDim.x);
  const int glo = (t0 < t1) ? batch[t0 * 64] : 0;   // local pool base graph

  // Stage W once (async; each wave copies distinct 1024B segments).
  constexpr int W1SEG = 128 * K1 / 1024;
  for (int s = wv; s < W1SEG; s += 8)
    ld_lds16(W1t + s * 1024 + lane * 16, &W1ls[s * 1024]);
  for (int s = wv; s < 16; s += 8)
    ld_lds16(W2t + s * 1024 + lane * 16, &W2ls[s * 1024]);

  // Zero local pool (512 floats, one per thread).
  poolLs[tx] = 0.f;
  if (tx < 128) {                          // fold bias1 into BN affine
    float s = gam[tx] * rsqrtf(var[tx] + 1e-5f);
    sc1[tx] = s;
    sh1[tx] = bet[tx] + (b1[tx] - mu[tx]) * s;
  } else if (tx < 256) {
    b2l[tx - 128] = b2[tx - 128];
  }

  int tile = t0;
  constexpr int ASEG = 64 * K1 / 1024;
  if (tile < t1) {
    const unsigned char* srcp = Ag + (size_t)tile * 64 * K1;
    for (int s = wv; s < ASEG; s += 8)
      ld_lds16(srcp + s * 1024 + lane * 16, &Als[s * 1024]);
  }
  __syncthreads();                         // drains W + A(tile)

  while (tile < t1) {
    // ---- GEMM1: Z = relu(BN(A @ W1 + b1)) ----
    f32x4 acc[4];
#pragma unroll
    for (int t4 = 0; t4 < 4; ++t4) acc[t4] = (f32x4)(0.f);
    const int am = rowGroup + m;
#pragma unroll
    for (int kc = 0; kc < K1 / 32; ++kc) {
      const int c16 = kc * 2 + (q >> 1);
      const int hb = (q & 1) << 3;
      long af = *(const long*)&Als[am * K1 + ((c16 ^ (am & CM1)) << 4) + hb];
#pragma unroll
      for (int t4 = 0; t4 < 4; ++t4) {
        const int bn = colHalf + t4 * 16 + m;
        long bf = *(const long*)&W1ls[bn * K1 + ((c16 ^ (bn & CM1)) << 4) + hb];
        acc[t4] = __builtin_amdgcn_mfma_f32_16x16x32_fp8_fp8(af, bf, acc[t4], 0, 0, 0);
      }
    }
#pragma unroll
    for (int t4 = 0; t4 < 4; ++t4) {       // epilogue -> Zls (fp8, swizzled)
      const int col = colHalf + t4 * 16 + m;
      const float s = sc1[col], hh = sh1[col];
#pragma unroll
      for (int reg = 0; reg < 4; ++reg) {
        const int r = rowGroup + q * 4 + reg;
        float z = fmaf(acc[t4][reg], s, hh);
        z = z > 0.f ? z : 0.f;
        Zls[r * 128 + (((col >> 4) ^ (r & 7)) << 4) + (col & 15)] = f2fp8(z);
      }
    }
    __syncthreads();                       // Zls ready; Als free
    const int nt = tile + 1;
    if (nt < t1) {                         // prefetch next A, overlaps GEMM2
      const unsigned char* srcp = Ag + (size_t)nt * 64 * K1;
      for (int s = wv; s < ASEG; s += 8)
        ld_lds16(srcp + s * 1024 + lane * 16, &Als[s * 1024]);
    }
    // ---- GEMM2: C = relu(Z @ W2 + b2) ----
#pragma unroll
    for (int t4 = 0; t4 < 4; ++t4) acc[t4] = (f32x4)(0.f);
#pragma unroll
    for (int kc = 0; kc < 4; ++kc) {
      const int c16 = kc * 2 + (q >> 1);
      const int hb = (q & 1) << 3;
      long af = *(const long*)&Zls[am * 128 + ((c16 ^ (am & 7)) << 4) + hb];
#pragma unroll
      for (int t4 = 0; t4 < 4; ++t4) {
        const int bn = colHalf + t4 * 16 + m;
        long bf = *(const long*)&W2ls[bn * 128 + ((c16 ^ (bn & 7)) << 4) + hb];
        acc[t4] = __builtin_amdgcn_mfma_f32_16x16x32_fp8_fp8(af, bf, acc[t4], 0, 0, 0);
      }
    }
    const int r0 = tile * 64 + rowGroup + q * 4;
    int gb4[4];
#pragma unroll
    for (int reg = 0; reg < 4; ++reg) gb4[reg] = (r0 + reg < n) ? batch[r0 + reg] : -1;
#pragma unroll
    for (int t4 = 0; t4 < 4; ++t4) {
      const int col = colHalf + t4 * 16 + m;
      float v[4];
#pragma unroll
      for (int reg = 0; reg < 4; ++reg) {
        float z = acc[t4][reg] + b2l[col];
        v[reg] = z > 0.f ? z : 0.f;
      }
      if constexpr (STORE) {
        // fp8 row: chunk (col>>4)^(row&7), byte col&15 (matches gather_h)
#pragma unroll
        for (int reg = 0; reg < 4; ++reg) {
          const int row = r0 + reg;
          if (row < n)
            Pout[(size_t)row * 128 + (((col >> 4) ^ (row & 7)) << 4) + (col & 15)] = f2fp8(v[reg]);
        }
      }
      int gcur = -1; float ps = 0.f;       // batch sorted -> run-length flush
#pragma unroll
      for (int reg = 0; reg < 4; ++reg) {
        if (gb4[reg] < 0) break;
        if (gb4[reg] != gcur) {
          if (gcur >= 0) {
            const int li = gcur - glo;
            if (li < 4) atomicAdd(&poolLs[li * H + col], ps);
            else        atomicAdd(&red[gcur * H + col], ps);
          }
          gcur = gb4[reg]; ps = v[reg];
        } else {
          ps += v[reg];
        }
      }
      if (gcur >= 0) {
        const int li = gcur - glo;
        if (li < 4) atomicAdd(&poolLs[li * H + col], ps);
        else        atomicAdd(&red[gcur * H + col], ps);
      }
    }
    __syncthreads();                       // drains prefetch; Zls free
    tile = nt;
  }

  // Flush local pool window (<=4 graphs) to global red.
  if (t0 < t1) {
    const int rhi = min(t1 * 64, n) - 1;
    const int ng = min(batch[rhi] - glo + 1, 4);
    for (int i = tx; i < ng * H; i += 512)
      atomicAdd(&red[glo * H + i], poolLs[i]);
  }
}

// ------- Head: read reduced pools + MLP + sigmoid ---------------------------

__global__ void head2(const float* __restrict__ red,
                      const float* __restrict__ l1w, const float* __restrict__ l1b,
                      const float* __restrict__ l2w, const float* __restrict__ l2b,
                      const float* __restrict__ l3w, const float* __restrict__ l3b,
                      float* __restrict__ out) {
  const int g = blockIdx.x;
  const int t = threadIdx.x;  // 256 threads
  __shared__ float hin[3 * H];
  __shared__ float t1[50];
  __shared__ float t2[20];
  for (int idx = t; idx < 3 * H; idx += 256) {
    const int l = idx >> 7, f = idx & 127;
    hin[idx] = red[(size_t)l * (GG * H) + (size_t)g * H + f];
  }
  __syncthreads();
  if (t < 50) {
    float s = l1b[t];
    for (int k = 0; k < 3 * H; ++k) s = fmaf(hin[k], l1w[k * 50 + t], s);
    t1[t] = s > 0.f ? s : 0.f;
  }
  __syncthreads();
  if (t < 20) {
    float s = l2b[t];
    for (int k = 0; k < 50; ++k) s = fmaf(t1[k], l2w[k * 20 + t], s);
    t2[t] = s > 0.f ? s : 0.f;
  }
  __syncthreads();
  if (t == 0) {
    float s = l3b[0];
    for (int k = 0; k < 20; ++k) s = fmaf(t2[k], l3w[k], s);
    out[g] = 1.f / (1.f + expf(-s));
  }
}

// ---------------- launch ----------------------------------------------------

extern "C" void kernel_launch(void* const* d_in, const int* in_sizes, int n_in,
                              void* d_out, int out_size, void* d_ws, size_t ws_size,
                              hipStream_t stream) {
  const float* x    = (const float*)d_in[0];
  const int* ei     = (const int*)d_in[1];
  const int* batch  = (const int*)d_in[2];
  const int N = in_sizes[2];
  const int E = in_sizes[1] / 2;
  const int* src = ei;
  const int* dst = ei + E;

  const float* w1[3]; const float* b1[3]; const float* gm[3]; const float* be[3];
  const float* mu[3]; const float* vr[3]; const float* w2[3]; const float* b2[3];
  for (int l = 0; l < 3; ++l) {
    int b = 3 + 8 * l;
    w1[l] = (const float*)d_in[b + 0];
    b1[l] = (const float*)d_in[b + 1];
    gm[l] = (const float*)d_in[b + 2];
    be[l] = (const float*)d_in[b + 3];
    mu[l] = (const float*)d_in[b + 4];
    vr[l] = (const float*)d_in[b + 5];
    w2[l] = (const float*)d_in[b + 6];
    b2[l] = (const float*)d_in[b + 7];
  }
  const float* l1w = (const float*)d_in[27];
  const float* l1b = (const float*)d_in[28];
  const float* l2w = (const float*)d_in[29];
  const float* l2b = (const float*)d_in[30];
  const float* l3w = (const float*)d_in[31];
  const float* l3b = (const float*)d_in[32];

  // workspace carve-up
  char* ws = (char*)d_ws;
  size_t off = 0;
  auto take = [&](size_t bytes) {
    size_t p = off;
    off += (bytes + 255) & ~(size_t)255;
    return p;
  };
  unsigned char* A   = (unsigned char*)(ws + take((size_t)N * H));        // agg (fp8, swizzled)
  unsigned char* P   = (unsigned char*)(ws + take((size_t)N * H));        // layer out (fp8, swizzled)
  unsigned char* x8  = (unsigned char*)(ws + take((size_t)N * 64));       // x as fp8 Nx64 swizzled
  float* red    = (float*)(ws + take((size_t)3 * GG * H * 4));            // 96 KB pooled sums
  int* rowptr   = (int*)(ws + take((size_t)(N + 1) * 4));
  int* deg      = (int*)(ws + take((size_t)N * 4));                       // node degrees
  int* cur      = (int*)(ws + take((size_t)N * 4));                       // scatter cursors
  int* blockTotal = (int*)(ws + take((size_t)256 * 4));
  int* srcList  = (int*)(ws + take((size_t)E * 4));
  unsigned char* Wt[6];
  for (int i = 0; i < 6; ++i) Wt[i] = (unsigned char*)(ws + take((size_t)H * H));
  (void)ws_size; (void)n_in; (void)out_size;

  const int NBLK = 256;
  const int XB = ((size_t)N * 64 + 1023) / 1024;
  const int SB = (N + 255) / 256;         // scan blocks (<= 256)
  const int GBH = (N + 31) / 32;          // gather_h blocks (32 nodes each)
  const int GBX = (N + 63) / 64;          // gather_x4 blocks (64 nodes each)

  // zero degree array (capture-legal async fill)
  hipMemsetAsync(deg, 0, (size_t)N * 4, stream);

  // prep2: deg hist + wconv + xconv + red zero, one wide launch
  PrepArgs pa;
  pa.dst = dst; pa.deg = deg; pa.E = E; pa.NBLK = NBLK;
  pa.w[0] = w1[0]; pa.K[0] = F_IN; pa.Kp[0] = 64;
  pa.w[1] = w2[0]; pa.K[1] = H;    pa.Kp[1] = H;
  pa.w[2] = w1[1]; pa.K[2] = H;    pa.Kp[2] = H;
  pa.w[3] = w2[1]; pa.K[3] = H;    pa.Kp[3] = H;
  pa.w[4] = w1[2]; pa.K[4] = H;    pa.Kp[4] = H;
  pa.w[5] = w2[2]; pa.K[5] = H;    pa.Kp[5] = H;
  for (int i = 0; i < 6; ++i) pa.o[i] = Wt[i];
  pa.x = x; pa.x8 = x8; pa.N = N; pa.XB = XB;
  pa.red = red;
  prep2<<<NBLK + 384 + XB + 24, 256, 0, stream>>>(pa);

  // CSR: hierarchical scan (wide) + direct scatter
  scanB<<<SB, 256, 0, stream>>>(deg, blockTotal, N);
  scanC<<<SB, 256, 0, stream>>>(deg, blockTotal, rowptr, cur, N, E, SB);
  csr_scatter<<<1024, 256, 0, stream>>>(src, dst, cur, srcList, E);

  // ---- layer 1 (K padded 33 -> 64) ----
  gather_x4<<<GBX, 256, 0, stream>>>(x8, rowptr, srcList, A, N);
  gin_mlp<64, true><<<512, 512, 0, stream>>>(
      A, Wt[0], Wt[1], b1[0], gm[0], be[0], mu[0], vr[0], b2[0],
      P, batch, red, N);

  // ---- layer 2 ----
  gather_h<<<GBH, 256, 0, stream>>>(P, rowptr, srcList, A, N);
  gin_mlp<128, true><<<512, 512, 0, stream>>>(
      A, Wt[2], Wt[3], b1[1], gm[1], be[1], mu[1], vr[1], b2[1],
      P, batch, red + (size_t)GG * H, N);

  // ---- layer 3 (h3 pooled only) ----
  gather_h<<<GBH, 256, 0, stream>>>(P, rowptr, srcList, A, N);
  gin_mlp<128, false><<<512, 512, 0, stream>>>(
      A, Wt[4], Wt[5], b1[2], gm[2], be[2], mu[2], vr[2], b2[2],
      nullptr, batch, red + (size_t)2 * GG * H, N);

  // ---- head (read reduced pools + MLP + sigmoid) ----
  head2<<<GG, 256, 0, stream>>>(red, l1w, l1b, l2w, l2b, l3w, l3b, (float*)d_out);
}

// Round 9
// 286.989 us; speedup vs baseline: 1.5828x; 1.1878x over previous
//
#include <hip/hip_runtime.h>
#include <math.h>

// N=50000 nodes, E=800000 edges, F_IN=33, H=128, G=64 graphs.
static constexpr int F_IN = 33;
static constexpr int H    = 128;
static constexpr int GG   = 64;

typedef __attribute__((ext_vector_type(4))) float f32x4;

// fp8 e4m3 (OCP on gfx950) encode/decode via HW cvt.
__device__ __forceinline__ unsigned char f2fp8(float f) {
  int pk = __builtin_amdgcn_cvt_pk_fp8_f32(f, f, 0, false);
  return (unsigned char)(pk & 0xff);
}

// Async global->LDS copy, 16B per lane, wave-uniform LDS base (lane-linear).
using gas_u32 = const __attribute__((address_space(1))) unsigned int*;
using las_u32 = __attribute__((address_space(3))) unsigned int*;
__device__ __forceinline__ void ld_lds16(const unsigned char* g, unsigned char* l) {
  __builtin_amdgcn_global_load_lds((gas_u32)(const void*)g, (las_u32)(void*)l, 16, 0, 0);
}

// ---------------- prep: csr hist + W conv(fp8) + x conv + red zero ----------
// R5-R8 lessons baked in: wide grid (R6: coop 256-block cap = 15x parallelism
// loss); bucket-sort CSR (R8: direct scatter = 53MB write amplification from
// random 4B stores; bucket sub-segments are append-style / write-combining).

struct PrepArgs {
  const int* dst; int* M; int E; int NB; int NBLK;
  const float* w[6]; unsigned char* o[6]; int K[6]; int Kp[6];
  const float* x; unsigned char* x8; int N; int XB;
  float* red;                               // 3 * GG * H f32, zeroed here
};

__global__ void prep(PrepArgs a) {
  const int b = blockIdx.x, tx = threadIdx.x;
  if (b < a.NBLK) {
    __shared__ int hist[256];
    for (int i = tx; i < a.NB; i += 256) hist[i] = 0;
    __syncthreads();
    const int chunk = (a.E + a.NBLK - 1) / a.NBLK;
    const int lo = b * chunk;
    const int hi = min(lo + chunk, a.E);
    for (int i = lo + tx; i < hi; i += 256)
      atomicAdd(&hist[a.dst[i] >> 8], 1);
    __syncthreads();
    for (int bb = tx; bb < a.NB; bb += 256)
      a.M[bb * a.NBLK + b] = hist[bb];
  } else if (b < a.NBLK + 384) {
    // W -> fp8, row nn = Kp bytes, 16B chunk c stored at c ^ (nn & (Kp/16-1))
    const int wb = b - a.NBLK;
    const int wi = wb >> 6;
    const int Kp = a.Kp[wi];
    const int i = (wb & 63) * 256 + tx;
    if (i < H * Kp) {
      const int nn = i / Kp, k = i - nn * Kp;
      float v = (k < a.K[wi]) ? a.w[wi][(size_t)k * H + nn] : 0.f;
      a.o[wi][(size_t)nn * Kp + (((k >> 4) ^ (nn & (Kp / 16 - 1))) << 4) + (k & 15)] = f2fp8(v);
    }
  } else if (b < a.NBLK + 384 + a.XB) {
    // x -> fp8, N x 64 rows (64B), 4 chunks of 16B, chunk c at c^(node&3)
    const int xb = b - a.NBLK - 384;
    for (int r = 0; r < 4; ++r) {
      const int idx = xb * 1024 + r * 256 + tx;
      const int node = idx >> 6, f = idx & 63;
      if (node < a.N) {
        float v = (f < F_IN) ? a.x[(size_t)node * F_IN + f] : 0.f;
        a.x8[(size_t)node * 64 + (((f >> 4) ^ (node & 3)) << 4) + (f & 15)] = f2fp8(v);
      }
    }
  } else {
    // zero red: 24 blocks x 256 threads x f32x4 = 3*GG*H floats
    const int zb = b - a.NBLK - 384 - a.XB;
    f32x4* r4 = (f32x4*)a.red;
    r4[zb * 256 + tx] = (f32x4)(0.f);
  }
}

// ---------------- CSR: per-bucket scan of M + bucket totals -----------------

__global__ void scanA(int* __restrict__ M, int* __restrict__ bucketTotal, int NBLK) {
  __shared__ int scn[256];
  const int b = blockIdx.x, t = threadIdx.x;
  int v = M[b * NBLK + t];
  scn[t] = v;
  __syncthreads();
  for (int off = 1; off < 256; off <<= 1) {
    int add = (t >= off) ? scn[t - off] : 0;
    __syncthreads();
    scn[t] += add;
    __syncthreads();
  }
  M[b * NBLK + t] = scn[t] - v;
  if (t == 255) bucketTotal[b] = scn[255];
}

__global__ void csr_p2(const int* __restrict__ src, const int* __restrict__ dst,
                       const int* __restrict__ M, const int* __restrict__ bucketTotal,
                       unsigned* __restrict__ tmp, int E, int NB) {
  __shared__ int scn[256];
  __shared__ int cur[256];
  const int tx = threadIdx.x, blk = blockIdx.x, nblk = gridDim.x;
  int v = (tx < NB) ? bucketTotal[tx] : 0;
  scn[tx] = v;
  __syncthreads();
  for (int off = 1; off < 256; off <<= 1) {
    int add = (tx >= off) ? scn[tx - off] : 0;
    __syncthreads();
    scn[tx] += add;
    __syncthreads();
  }
  int e = scn[tx] - v;                    // exclusive bucket offset
  __syncthreads();
  scn[tx] = e;
  __syncthreads();
  for (int b = tx; b < NB; b += 256) cur[b] = M[b * nblk + blk] + scn[b];
  __syncthreads();
  const int chunk = (E + nblk - 1) / nblk;
  const int lo = blk * chunk;
  const int hi = min(lo + chunk, E);
  for (int i = lo + tx; i < hi; i += 256) {
    int d = dst[i];
    int pos = atomicAdd(&cur[d >> 8], 1);
    tmp[pos] = ((unsigned)src[i] << 8) | (unsigned)(d & 255);   // src < 2^24
  }
}

__global__ void csr_p3(const unsigned* __restrict__ tmp, const int* __restrict__ bucketTotal,
                       int* __restrict__ rowptr, int* __restrict__ srcList,
                       int n, int E, int NB) {
  __shared__ int scn[256];
  __shared__ int hist[256];
  __shared__ int s2[256];
  const int b = blockIdx.x, tx = threadIdx.x;
  int v = (tx < NB) ? bucketTotal[tx] : 0;
  scn[tx] = v;
  __syncthreads();
  for (int off = 1; off < 256; off <<= 1) {
    int add = (tx >= off) ? scn[tx - off] : 0;
    __syncthreads();
    scn[tx] += add;
    __syncthreads();
  }
  int e = scn[tx] - v;
  __syncthreads();
  scn[tx] = e;
  __syncthreads();
  const int segStart = scn[b];
  const int segEnd = (b + 1 < NB) ? scn[b + 1] : E;
  if (b == 0 && tx == 0) rowptr[n] = E;
  const int nodeBase = b << 8;
  hist[tx] = 0;
  __syncthreads();
  for (int i = segStart + tx; i < segEnd; i += 256)
    atomicAdd(&hist[tmp[i] & 255u], 1);
  __syncthreads();
  int hv = hist[tx];
  s2[tx] = hv;
  __syncthreads();
  for (int off = 1; off < 256; off <<= 1) {
    int add = (tx >= off) ? s2[tx - off] : 0;
    __syncthreads();
    s2[tx] += add;
    __syncthreads();
  }
  int ex = s2[tx] - hv;                    // exclusive prefix within bucket
  if (nodeBase + tx < n) rowptr[nodeBase + tx] = segStart + ex;
  hist[tx] = ex;                           // reuse as cursor
  __syncthreads();
  for (int i = segStart + tx; i < segEnd; i += 256) {
    unsigned ee = tmp[i];
    int pos = atomicAdd(&hist[ee & 255u], 1);
    srcList[segStart + pos] = (int)(ee >> 8);
  }
}

// ---------------- Aggregation (gather), fp8 rows -> fp8 out -----------------
// Line-throughput bound (R2/R3/R5 evidence). R4 known-good form.

__global__ void gather_h(const unsigned char* __restrict__ h8, const int* __restrict__ rowptr,
                         const int* __restrict__ srcList, unsigned char* __restrict__ out, int n) {
  const int tx = threadIdx.x;
  const int node = blockIdx.x * 32 + (tx >> 3);   // 8-lane group per node
  if (node >= n) return;
  const int lane = tx & 63;
  const int l8 = lane & 7;                // 16B chunk within fp8 row
  const int gbase = lane & 56;
  const uint4* h16 = (const uint4*)h8;    // fp8 row = 8 uint4 (128B)
  auto roff = [&](int r) { return (size_t)r * 8 + (l8 ^ (r & 7)); };

  const int beg = rowptr[node], end = rowptr[node + 1];
  float a[16];
#pragma unroll
  for (int i = 0; i < 16; ++i) a[i] = 0.f;
  auto addv = [&](uint4 vv) {
    const unsigned* w = (const unsigned*)&vv;
#pragma unroll
    for (int c = 0; c < 4; ++c) {
      a[c * 4 + 0] += __builtin_amdgcn_cvt_f32_fp8(w[c], 0);
      a[c * 4 + 1] += __builtin_amdgcn_cvt_f32_fp8(w[c], 1);
      a[c * 4 + 2] += __builtin_amdgcn_cvt_f32_fp8(w[c], 2);
      a[c * 4 + 3] += __builtin_amdgcn_cvt_f32_fp8(w[c], 3);
    }
  };

  for (int base = beg; base < end; base += 8) {
    const int cnt = min(8, end - base);
    int myidx = (l8 < cnt) ? srcList[base + l8] : 0;
#pragma unroll
    for (int j = 0; j < 8; j += 4) {
      if (j >= cnt) break;
      int s[4]; uint4 v[4];
#pragma unroll
      for (int k = 0; k < 4; ++k) s[k] = __shfl(myidx, gbase + min(j + k, cnt - 1));
#pragma unroll
      for (int k = 0; k < 4; ++k) v[k] = h16[roff(s[k])];
#pragma unroll
      for (int k = 0; k < 4; ++k) if (j + k < cnt) addv(v[k]);
    }
  }
  addv(h16[roff(node)]);                  // self term
  // 16 f32 -> 16 fp8 bytes = this lane's 16B chunk l8 of the A row
  unsigned w0 = __builtin_amdgcn_cvt_pk_fp8_f32(a[0], a[1], 0, false);
  w0 = __builtin_amdgcn_cvt_pk_fp8_f32(a[2], a[3], w0, true);
  unsigned w1 = __builtin_amdgcn_cvt_pk_fp8_f32(a[4], a[5], 0, false);
  w1 = __builtin_amdgcn_cvt_pk_fp8_f32(a[6], a[7], w1, true);
  unsigned w2 = __builtin_amdgcn_cvt_pk_fp8_f32(a[8], a[9], 0, false);
  w2 = __builtin_amdgcn_cvt_pk_fp8_f32(a[10], a[11], w2, true);
  unsigned w3 = __builtin_amdgcn_cvt_pk_fp8_f32(a[12], a[13], 0, false);
  w3 = __builtin_amdgcn_cvt_pk_fp8_f32(a[14], a[15], w3, true);
  uint4 o; o.x = w0; o.y = w1; o.z = w2; o.w = w3;
  ((uint4*)out)[(size_t)node * 8 + (l8 ^ (node & 7))] = o;
}

// Layer-1 gather on x8 (fp8 Nx64 swizzled, 64B rows = 4 uint4) -> A fp8 64B.

__global__ void gather_x4(const unsigned char* __restrict__ x8, const int* __restrict__ rowptr,
                          const int* __restrict__ srcList, unsigned char* __restrict__ out, int n) {
  const int tx = threadIdx.x;
  const int node = blockIdx.x * 64 + (tx >> 2);   // 4-lane group per node
  if (node >= n) return;
  const int lane = tx & 63;
  const int l4 = lane & 3;                // 16B chunk within fp8 row
  const int gbase = lane & 60;
  const uint4* h16 = (const uint4*)x8;    // fp8 row = 4 uint4 (64B)
  auto roff = [&](int r) { return (size_t)r * 4 + (l4 ^ (r & 3)); };

  const int beg = rowptr[node], end = rowptr[node + 1];
  float a[16];
#pragma unroll
  for (int i = 0; i < 16; ++i) a[i] = 0.f;
  auto addv = [&](uint4 vv) {
    const unsigned* w = (const unsigned*)&vv;
#pragma unroll
    for (int c = 0; c < 4; ++c) {
      a[c * 4 + 0] += __builtin_amdgcn_cvt_f32_fp8(w[c], 0);
      a[c * 4 + 1] += __builtin_amdgcn_cvt_f32_fp8(w[c], 1);
      a[c * 4 + 2] += __builtin_amdgcn_cvt_f32_fp8(w[c], 2);
      a[c * 4 + 3] += __builtin_amdgcn_cvt_f32_fp8(w[c], 3);
    }
  };

  for (int base = beg; base < end; base += 4) {
    const int cnt = min(4, end - base);
    int myidx = (l4 < cnt) ? srcList[base + l4] : 0;
    int s[4]; uint4 v[4];
#pragma unroll
    for (int k = 0; k < 4; ++k) s[k] = __shfl(myidx, gbase + min(k, cnt - 1));
#pragma unroll
    for (int k = 0; k < 4; ++k) v[k] = h16[roff(s[k])];
#pragma unroll
    for (int k = 0; k < 4; ++k) if (k < cnt) addv(v[k]);
  }
  addv(h16[roff(node)]);                  // self term
  unsigned w0 = __builtin_amdgcn_cvt_pk_fp8_f32(a[0], a[1], 0, false);
  w0 = __builtin_amdgcn_cvt_pk_fp8_f32(a[2], a[3], w0, true);
  unsigned w1 = __builtin_amdgcn_cvt_pk_fp8_f32(a[4], a[5], 0, false);
  w1 = __builtin_amdgcn_cvt_pk_fp8_f32(a[6], a[7], w1, true);
  unsigned w2 = __builtin_amdgcn_cvt_pk_fp8_f32(a[8], a[9], 0, false);
  w2 = __builtin_amdgcn_cvt_pk_fp8_f32(a[10], a[11], w2, true);
  unsigned w3 = __builtin_amdgcn_cvt_pk_fp8_f32(a[12], a[13], 0, false);
  w3 = __builtin_amdgcn_cvt_pk_fp8_f32(a[14], a[15], w3, true);
  uint4 o; o.x = w0; o.y = w1; o.z = w2; o.w = w3;
  ((uint4*)out)[(size_t)node * 4 + (l4 ^ (node & 3))] = o;
}

// -------- Fused GIN MLP (all-fp8): C = relu(relu(BN(A@W1)) @ W2 + b2) -------
// fp8 MFMA + fp8 LDS tiles + 4-graph local pool (R4 known-good).

template <int K1, bool STORE>
__global__ __launch_bounds__(512, 4) void gin_mlp(
    const unsigned char* __restrict__ Ag,    // n x K1 fp8 (swizzled rows)
    const unsigned char* __restrict__ W1t,   // 128 x K1 fp8 (swizzled)
    const unsigned char* __restrict__ W2t,   // 128 x 128 fp8 (swizzled)
    const float* __restrict__ b1, const float* __restrict__ gam,
    const float* __restrict__ bet, const float* __restrict__ mu,
    const float* __restrict__ var, const float* __restrict__ b2,
    unsigned char* __restrict__ Pout,        // n x 128 fp8 (swizzled) or null
    const int* __restrict__ batch,
    float* __restrict__ red,                 // GG*H f32, pre-zeroed; atomic dst
    int n) {
  constexpr int CM1 = K1 / 16 - 1;           // A/W1 chunk-swizzle mask
  __shared__ __align__(16) unsigned char W1ls[128 * K1];
  __shared__ __align__(16) unsigned char W2ls[128 * 128];
  __shared__ __align__(16) unsigned char Als[64 * K1];
  __shared__ __align__(16) unsigned char Zls[64 * 128];
  __shared__ float poolLs[4 * H];            // 2 KB local-graph pool window
  __shared__ float sc1[128], sh1[128], b2l[128];

  const int tx = threadIdx.x;
  const int wv = tx >> 6;                 // wave 0..7
  const int lane = tx & 63;
  const int q = lane >> 4, m = lane & 15;
  const int rowGroup = (wv >> 1) * 16;    // 0,16,32,48
  const int colHalf = (wv & 1) * 64;
  const int ntiles = (n + 63) >> 6;
  // contiguous tile range for this block
  const int t0 = (int)(((long long)ntiles * blockIdx.x) / gridDim.x);
  const int t1 = (int)(((long long)ntiles * (blockIdx.x + 1)) / gridDim.x);
  const int glo = (t0 < t1) ? batch[t0 * 64] : 0;   // local pool base graph

  // Stage W once (async; each wave copies distinct 1024B segments).
  constexpr int W1SEG = 128 * K1 / 1024;
  for (int s = wv; s < W1SEG; s += 8)
    ld_lds16(W1t + s * 1024 + lane * 16, &W1ls[s * 1024]);
  for (int s = wv; s < 16; s += 8)
    ld_lds16(W2t + s * 1024 + lane * 16, &W2ls[s * 1024]);

  // Zero local pool (512 floats, one per thread).
  poolLs[tx] = 0.f;
  if (tx < 128) {                          // fold bias1 into BN affine
    float s = gam[tx] * rsqrtf(var[tx] + 1e-5f);
    sc1[tx] = s;
    sh1[tx] = bet[tx] + (b1[tx] - mu[tx]) * s;
  } else if (tx < 256) {
    b2l[tx - 128] = b2[tx - 128];
  }

  int tile = t0;
  constexpr int ASEG = 64 * K1 / 1024;
  if (tile < t1) {
    const unsigned char* srcp = Ag + (size_t)tile * 64 * K1;
    for (int s = wv; s < ASEG; s += 8)
      ld_lds16(srcp + s * 1024 + lane * 16, &Als[s * 1024]);
  }
  __syncthreads();                         // drains W + A(tile)

  while (tile < t1) {
    // ---- GEMM1: Z = relu(BN(A @ W1 + b1)) ----
    f32x4 acc[4];
#pragma unroll
    for (int t4 = 0; t4 < 4; ++t4) acc[t4] = (f32x4)(0.f);
    const int am = rowGroup + m;
#pragma unroll
    for (int kc = 0; kc < K1 / 32; ++kc) {
      const int c16 = kc * 2 + (q >> 1);
      const int hb = (q & 1) << 3;
      long af = *(const long*)&Als[am * K1 + ((c16 ^ (am & CM1)) << 4) + hb];
#pragma unroll
      for (int t4 = 0; t4 < 4; ++t4) {
        const int bn = colHalf + t4 * 16 + m;
        long bf = *(const long*)&W1ls[bn * K1 + ((c16 ^ (bn & CM1)) << 4) + hb];
        acc[t4] = __builtin_amdgcn_mfma_f32_16x16x32_fp8_fp8(af, bf, acc[t4], 0, 0, 0);
      }
    }
#pragma unroll
    for (int t4 = 0; t4 < 4; ++t4) {       // epilogue -> Zls (fp8, swizzled)
      const int col = colHalf + t4 * 16 + m;
      const float s = sc1[col], hh = sh1[col];
#pragma unroll
      for (int reg = 0; reg < 4; ++reg) {
        const int r = rowGroup + q * 4 + reg;
        float z = fmaf(acc[t4][reg], s, hh);
        z = z > 0.f ? z : 0.f;
        Zls[r * 128 + (((col >> 4) ^ (r & 7)) << 4) + (col & 15)] = f2fp8(z);
      }
    }
    __syncthreads();                       // Zls ready; Als free
    const int nt = tile + 1;
    if (nt < t1) {                         // prefetch next A, overlaps GEMM2
      const unsigned char* srcp = Ag + (size_t)nt * 64 * K1;
      for (int s = wv; s < ASEG; s += 8)
        ld_lds16(srcp + s * 1024 + lane * 16, &Als[s * 1024]);
    }
    // ---- GEMM2: C = relu(Z @ W2 + b2) ----
#pragma unroll
    for (int t4 = 0; t4 < 4; ++t4) acc[t4] = (f32x4)(0.f);
#pragma unroll
    for (int kc = 0; kc < 4; ++kc) {
      const int c16 = kc * 2 + (q >> 1);
      const int hb = (q & 1) << 3;
      long af = *(const long*)&Zls[am * 128 + ((c16 ^ (am & 7)) << 4) + hb];
#pragma unroll
      for (int t4 = 0; t4 < 4; ++t4) {
        const int bn = colHalf + t4 * 16 + m;
        long bf = *(const long*)&W2ls[bn * 128 + ((c16 ^ (bn & 7)) << 4) + hb];
        acc[t4] = __builtin_amdgcn_mfma_f32_16x16x32_fp8_fp8(af, bf, acc[t4], 0, 0, 0);
      }
    }
    const int r0 = tile * 64 + rowGroup + q * 4;
    int gb4[4];
#pragma unroll
    for (int reg = 0; reg < 4; ++reg) gb4[reg] = (r0 + reg < n) ? batch[r0 + reg] : -1;
#pragma unroll
    for (int t4 = 0; t4 < 4; ++t4) {
      const int col = colHalf + t4 * 16 + m;
      float v[4];
#pragma unroll
      for (int reg = 0; reg < 4; ++reg) {
        float z = acc[t4][reg] + b2l[col];
        v[reg] = z > 0.f ? z : 0.f;
      }
      if constexpr (STORE) {
        // fp8 row: chunk (col>>4)^(row&7), byte col&15 (matches gather_h)
#pragma unroll
        for (int reg = 0; reg < 4; ++reg) {
          const int row = r0 + reg;
          if (row < n)
            Pout[(size_t)row * 128 + (((col >> 4) ^ (row & 7)) << 4) + (col & 15)] = f2fp8(v[reg]);
        }
      }
      int gcur = -1; float ps = 0.f;       // batch sorted -> run-length flush
#pragma unroll
      for (int reg = 0; reg < 4; ++reg) {
        if (gb4[reg] < 0) break;
        if (gb4[reg] != gcur) {
          if (gcur >= 0) {
            const int li = gcur - glo;
            if (li < 4) atomicAdd(&poolLs[li * H + col], ps);
            else        atomicAdd(&red[gcur * H + col], ps);
          }
          gcur = gb4[reg]; ps = v[reg];
        } else {
          ps += v[reg];
        }
      }
      if (gcur >= 0) {
        const int li = gcur - glo;
        if (li < 4) atomicAdd(&poolLs[li * H + col], ps);
        else        atomicAdd(&red[gcur * H + col], ps);
      }
    }
    __syncthreads();                       // drains prefetch; Zls free
    tile = nt;
  }

  // Flush local pool window (<=4 graphs) to global red.
  if (t0 < t1) {
    const int rhi = min(t1 * 64, n) - 1;
    const int ng = min(batch[rhi] - glo + 1, 4);
    for (int i = tx; i < ng * H; i += 512)
      atomicAdd(&red[glo * H + i], poolLs[i]);
  }
}

// ------- Head: read reduced pools + MLP + sigmoid ---------------------------

__global__ void head2(const float* __restrict__ red,
                      const float* __restrict__ l1w, const float* __restrict__ l1b,
                      const float* __restrict__ l2w, const float* __restrict__ l2b,
                      const float* __restrict__ l3w, const float* __restrict__ l3b,
                      float* __restrict__ out) {
  const int g = blockIdx.x;
  const int t = threadIdx.x;  // 256 threads
  __shared__ float hin[3 * H];
  __shared__ float t1[50];
  __shared__ float t2[20];
  for (int idx = t; idx < 3 * H; idx += 256) {
    const int l = idx >> 7, f = idx & 127;
    hin[idx] = red[(size_t)l * (GG * H) + (size_t)g * H + f];
  }
  __syncthreads();
  if (t < 50) {
    float s = l1b[t];
    for (int k = 0; k < 3 * H; ++k) s = fmaf(hin[k], l1w[k * 50 + t], s);
    t1[t] = s > 0.f ? s : 0.f;
  }
  __syncthreads();
  if (t < 20) {
    float s = l2b[t];
    for (int k = 0; k < 50; ++k) s = fmaf(t1[k], l2w[k * 20 + t], s);
    t2[t] = s > 0.f ? s : 0.f;
  }
  __syncthreads();
  if (t == 0) {
    float s = l3b[0];
    for (int k = 0; k < 20; ++k) s = fmaf(t2[k], l3w[k], s);
    out[g] = 1.f / (1.f + expf(-s));
  }
}

// ---------------- launch ----------------------------------------------------

extern "C" void kernel_launch(void* const* d_in, const int* in_sizes, int n_in,
                              void* d_out, int out_size, void* d_ws, size_t ws_size,
                              hipStream_t stream) {
  const float* x    = (const float*)d_in[0];
  const int* ei     = (const int*)d_in[1];
  const int* batch  = (const int*)d_in[2];
  const int N = in_sizes[2];
  const int E = in_sizes[1] / 2;
  const int* src = ei;
  const int* dst = ei + E;

  const float* w1[3]; const float* b1[3]; const float* gm[3]; const float* be[3];
  const float* mu[3]; const float* vr[3]; const float* w2[3]; const float* b2[3];
  for (int l = 0; l < 3; ++l) {
    int b = 3 + 8 * l;
    w1[l] = (const float*)d_in[b + 0];
    b1[l] = (const float*)d_in[b + 1];
    gm[l] = (const float*)d_in[b + 2];
    be[l] = (const float*)d_in[b + 3];
    mu[l] = (const float*)d_in[b + 4];
    vr[l] = (const float*)d_in[b + 5];
    w2[l] = (const float*)d_in[b + 6];
    b2[l] = (const float*)d_in[b + 7];
  }
  const float* l1w = (const float*)d_in[27];
  const float* l1b = (const float*)d_in[28];
  const float* l2w = (const float*)d_in[29];
  const float* l2b = (const float*)d_in[30];
  const float* l3w = (const float*)d_in[31];
  const float* l3b = (const float*)d_in[32];

  // workspace carve-up
  char* ws = (char*)d_ws;
  size_t off = 0;
  auto take = [&](size_t bytes) {
    size_t p = off;
    off += (bytes + 255) & ~(size_t)255;
    return p;
  };
  unsigned char* A   = (unsigned char*)(ws + take((size_t)N * H));        // agg (fp8, swizzled)
  unsigned char* P   = (unsigned char*)(ws + take((size_t)N * H));        // layer out (fp8, swizzled)
  unsigned char* x8  = (unsigned char*)(ws + take((size_t)N * 64));       // x as fp8 Nx64 swizzled
  float* red    = (float*)(ws + take((size_t)3 * GG * H * 4));            // 96 KB pooled sums
  int* rowptr   = (int*)(ws + take((size_t)(N + 1) * 4));
  int* M        = (int*)(ws + take((size_t)256 * 256 * 4));               // bucket counts/offsets
  int* srcList  = (int*)(ws + take((size_t)E * 4));
  unsigned* tmp = (unsigned*)(ws + take((size_t)E * 4));                  // packed (src<<8|dstLocal)
  int* bucketTotal = (int*)(ws + take((size_t)256 * 4));
  unsigned char* Wt[6];
  for (int i = 0; i < 6; ++i) Wt[i] = (unsigned char*)(ws + take((size_t)H * H));
  (void)ws_size; (void)n_in; (void)out_size;

  const int NBLK = 256;
  const int NB = (N + 255) >> 8;          // buckets of 256 nodes (<= 256)
  const int XB = ((size_t)N * 64 + 1023) / 1024;
  const int GBH = (N + 31) / 32;          // gather_h blocks (32 nodes each)
  const int GBX = (N + 63) / 64;          // gather_x4 blocks (64 nodes each)

  // prep: csr hist + wconv + xconv + red zero, one launch
  PrepArgs pa;
  pa.dst = dst; pa.M = M; pa.E = E; pa.NB = NB; pa.NBLK = NBLK;
  pa.w[0] = w1[0]; pa.K[0] = F_IN; pa.Kp[0] = 64;
  pa.w[1] = w2[0]; pa.K[1] = H;    pa.Kp[1] = H;
  pa.w[2] = w1[1]; pa.K[2] = H;    pa.Kp[2] = H;
  pa.w[3] = w2[1]; pa.K[3] = H;    pa.Kp[3] = H;
  pa.w[4] = w1[2]; pa.K[4] = H;    pa.Kp[4] = H;
  pa.w[5] = w2[2]; pa.K[5] = H;    pa.Kp[5] = H;
  for (int i = 0; i < 6; ++i) pa.o[i] = Wt[i];
  pa.x = x; pa.x8 = x8; pa.N = N; pa.XB = XB;
  pa.red = red;
  prep<<<NBLK + 384 + XB + 24, 256, 0, stream>>>(pa);

  // CSR: per-bucket scan, scatter to tmp, final sort into srcList + rowptr
  scanA<<<NB, 256, 0, stream>>>(M, bucketTotal, NBLK);
  csr_p2<<<NBLK, 256, 0, stream>>>(src, dst, M, bucketTotal, tmp, E, NB);
  csr_p3<<<NB, 256, 0, stream>>>(tmp, bucketTotal, rowptr, srcList, N, E, NB);

  // ---- layer 1 (K padded 33 -> 64) ----
  gather_x4<<<GBX, 256, 0, stream>>>(x8, rowptr, srcList, A, N);
  gin_mlp<64, true><<<512, 512, 0, stream>>>(
      A, Wt[0], Wt[1], b1[0], gm[0], be[0], mu[0], vr[0], b2[0],
      P, batch, red, N);

  // ---- layer 2 ----
  gather_h<<<GBH, 256, 0, stream>>>(P, rowptr, srcList, A, N);
  gin_mlp<128, true><<<512, 512, 0, stream>>>(
      A, Wt[2], Wt[3], b1[1], gm[1], be[1], mu[1], vr[1], b2[1],
      P, batch, red + (size_t)GG * H, N);

  // ---- layer 3 (h3 pooled only) ----
  gather_h<<<GBH, 256, 0, stream>>>(P, rowptr, srcList, A, N);
  gin_mlp<128, false><<<512, 512, 0, stream>>>(
      A, Wt[4], Wt[5], b1[2], gm[2], be[2], mu[2], vr[2], b2[2],
      nullptr, batch, red + (size_t)2 * GG * H, N);

  // ---- head (read reduced pools + MLP + sigmoid) ----
  head2<<<GG, 256, 0, stream>>>(red, l1w, l1b, l2w, l2b, l3w, l3b, (float*)d_out);
}